// Round 30
// baseline (205.324 us; speedup 1.0000x reference)
//
#include <hip/hip_runtime.h>
#include <hip/hip_bf16.h>

// FraudSNN fused kernel: GEMM (bf16 MFMA) + LIF recurrence, T=10, F=256, H=512.
// R30: 1 barrier per 2 t-steps. The barrier ladder (5->3->2->1 bars/t gave
// 285->240->226->178) continues: 4-buffer parity xt[2 par][2 tl]; per iteration
// (5 total): loads(t+2) | GEMM(t),LIF(t) | write xt[npar][0], loads(t+3) |
// GEMM(t+1),LIF(t+1) | write xt[npar][1] | ONE barrier. GEMMs stay sequential
// (acc[2][4] each) - no R15/R18/R20 register fusion blowup. Phase A eliminated;
// staging loads have multi-phase cover; deferred LIF2 unchanged.
// LDS 111.9 KB (mem 32.8 + xt 67.6 + cur2 11.5); peak live ~120 regs.

typedef short short8 __attribute__((ext_vector_type(8)));
typedef float f32x4 __attribute__((ext_vector_type(4)));

__device__ __forceinline__ unsigned short bfbits(float f) {
  union { __hip_bfloat16 h; unsigned short u; } c;
  c.h = __float2bfloat16(f);   // hardware RNE
  return c.u;
}

__device__ __forceinline__ unsigned int bfpack(float a, float b) {
  return (unsigned int)bfbits(a) | ((unsigned int)bfbits(b) << 16);
}

// sigmoid(10*(m-1)) = 1 / (1 + exp2(14.4269504*(1-m)))
__device__ __forceinline__ float spike10(float m) {
  float e = __builtin_amdgcn_exp2f(fmaf(m, -14.4269504f, 14.4269504f));
  return __builtin_amdgcn_rcpf(1.0f + e);
}

__device__ __forceinline__ void lif4(f32x4& mv, const f32x4 av, float w2c, float pr[4]) {
#pragma unroll
  for (int e = 0; e < 4; ++e) {
    float m   = fmaf(mv[e], 0.9f, av[e]);     // beta*mem + cur1
    float spk = spike10(m);
    mv[e] = m - spk;
    pr[e] = fmaf(spk, w2c, pr[e]);
  }
}

__global__ void w1_to_bf16(const float* __restrict__ w1, unsigned short* __restrict__ o) {
  int i = blockIdx.x * 256 + threadIdx.x;      // 32768 float4s
  float4 v = reinterpret_cast<const float4*>(w1)[i];
  reinterpret_cast<uint2*>(o)[i] = make_uint2(bfpack(v.x, v.y), bfpack(v.z, v.w));
}

__device__ __forceinline__ short8 cvt_frag(const float* p) {
  const float4 v0 = *reinterpret_cast<const float4*>(p);
  const float4 v1 = *reinterpret_cast<const float4*>(p + 4);
  union { unsigned int u[4]; short8 s; } cv;
  cv.u[0] = bfpack(v0.x, v0.y);
  cv.u[1] = bfpack(v0.z, v0.w);
  cv.u[2] = bfpack(v1.x, v1.y);
  cv.u[3] = bfpack(v1.z, v1.w);
  return cv.s;
}

// 512 threads = 8 waves. Block: 32 batch rows; wave w owns 32 rows x h in [w*64, w*64+64).
template <bool USE_WS>
__global__
__attribute__((amdgpu_flat_work_group_size(512, 512)))
void snn_main(const float* __restrict__ x,
              const unsigned short* __restrict__ w1bf,  // bf16 W1 (if USE_WS)
              const float* __restrict__ w1f,            // fp32 W1 (fallback)
              const float* __restrict__ b1,
              const float* __restrict__ w2,
              const float* __restrict__ b2,
              float* __restrict__ out)
{
  __shared__ __align__(16) float mem_lds[4][512][4];             // 32,768 B
  __shared__ __align__(16) unsigned short xt[2][2][2][32][132];  // [par][tl][half][row][col] 67,584 B
  __shared__ float cur2_lds[10][32][9];                          // [t][row][wave] 11,520 B
                                                                 // total 111,872 B

  const int tid  = threadIdx.x;
  const int lane = tid & 63;
  const int wave = tid >> 6;          // 0..7
  const int l15  = lane & 15;
  const int lq   = lane >> 4;         // 0..3
  const long b0  = (long)blockIdx.x * 32;
  const int h0   = wave * 64;         // 4 col-tiles of 16

  float w2l[4], b1l[4];
#pragma unroll
  for (int ct = 0; ct < 4; ++ct) {
    int h = h0 + ct * 16 + l15;
    w2l[ct] = w2[h];
    b1l[ct] = b1[h];
  }

#pragma unroll
  for (int p = 0; p < 4; ++p) {
    f32x4 z = {0.f, 0.f, 0.f, 0.f};
    *reinterpret_cast<f32x4*>(&mem_lds[p][tid][0]) = z;
  }
  // planes 4..7 (rt1, all ct) in registers: 16 VGPR
  f32x4 m4 = {0.f, 0.f, 0.f, 0.f}, m5 = m4, m6 = m4, m7 = m4;

  // staging: thread -> row sr (0..31), float4 col sc (0..15); 4 float4 per t
  const int sr = tid >> 4;
  const int sc = tid & 15;
  const float* xrow = x + (b0 + sr) * 2560;

  const unsigned short* wb = w1bf + (h0 + l15) * 256 + lq * 8;
  const float*          wf = w1f  + (h0 + l15) * 256 + lq * 8;

  // prologue: stage t=0 -> xt[0][0], t=1 -> xt[0][1]
#pragma unroll
  for (int tl = 0; tl < 2; ++tl)
#pragma unroll
    for (int j = 0; j < 4; ++j) {
      const float4 v = *reinterpret_cast<const float4*>(xrow + tl * 256 + (sc + j * 16) * 4);
      *reinterpret_cast<uint2*>(&xt[0][tl][j >> 1][sr][(sc + (j & 1) * 16) * 4]) =
          make_uint2(bfpack(v.x, v.y), bfpack(v.z, v.w));
    }
  __syncthreads();

#pragma unroll 1
  for (int ii = 0; ii < 5; ++ii) {
    const int par  = ii & 1;
    const int npar = par ^ 1;
    const int t0   = 2 * ii;

    // ---- issue raw loads for t0+2 (next iter, slot 0); in flight under GEMM(t0) ----
    float4 pfrA[4];
    {
      const int ta = (ii < 4) ? t0 + 2 : 8;   // tail: harmless re-read
#pragma unroll
      for (int j = 0; j < 4; ++j)
        pfrA[j] = *reinterpret_cast<const float4*>(xrow + ta * 256 + (sc + j * 16) * 4);
    }

    // ================= GEMM(t0) from xt[par][0] + LIF(t0) =================
    {
      f32x4 acc[2][4];
#pragma unroll
      for (int rt = 0; rt < 2; ++rt)
#pragma unroll
        for (int c = 0; c < 4; ++c) {
          f32x4 cc = { b1l[c], b1l[c], b1l[c], b1l[c] };
          acc[rt][c] = cc;
        }
      __builtin_amdgcn_s_setprio(1);
#pragma unroll
      for (int kk = 0; kk < 8; ++kk) {
        short8 a[2], bfr[4];
#pragma unroll
        for (int rt = 0; rt < 2; ++rt)
          a[rt] = *reinterpret_cast<const short8*>(
              &xt[par][0][kk >> 2][rt * 16 + l15][(kk & 3) * 32 + lq * 8]);
#pragma unroll
        for (int c = 0; c < 4; ++c) {
          if constexpr (USE_WS)
            bfr[c] = *reinterpret_cast<const short8*>(wb + c * 4096 + kk * 32);
          else
            bfr[c] = cvt_frag(wf + c * 4096 + kk * 32);
        }
#pragma unroll
        for (int rt = 0; rt < 2; ++rt)
#pragma unroll
          for (int c = 0; c < 4; ++c)
            acc[rt][c] = __builtin_amdgcn_mfma_f32_16x16x32_bf16(a[rt], bfr[c], acc[rt][c], 0, 0, 0);
      }
      __builtin_amdgcn_s_setprio(0);

#pragma unroll
      for (int rt = 0; rt < 2; ++rt) {
        float pr[4] = {0.f, 0.f, 0.f, 0.f};
#pragma unroll
        for (int c = 0; c < 4; ++c) {
          const int p = rt * 4 + c;
          if (p < 4) {
            f32x4* slot = reinterpret_cast<f32x4*>(&mem_lds[p][tid][0]);
            f32x4 mv = *slot;
            lif4(mv, acc[rt][c], w2l[c], pr);
            *slot = mv;
          } else if (p == 4) lif4(m4, acc[rt][c], w2l[c], pr);
          else if (p == 5)   lif4(m5, acc[rt][c], w2l[c], pr);
          else if (p == 6)   lif4(m6, acc[rt][c], w2l[c], pr);
          else               lif4(m7, acc[rt][c], w2l[c], pr);
        }
#pragma unroll
        for (int e = 0; e < 4; ++e) {
          float v = pr[e];
          v += __shfl_xor(v, 1); v += __shfl_xor(v, 2);
          v += __shfl_xor(v, 4); v += __shfl_xor(v, 8);
          if (l15 == 0) cur2_lds[t0][rt * 16 + lq * 4 + e][wave] = v;
        }
      }
    }

    // ---- pack+write t0+2 -> xt[npar][0] (loads covered by GEMM+LIF(t0));
    //      issue raw loads for t0+3 ----
#pragma unroll
    for (int j = 0; j < 4; ++j)
      *reinterpret_cast<uint2*>(&xt[npar][0][j >> 1][sr][(sc + (j & 1) * 16) * 4]) =
          make_uint2(bfpack(pfrA[j].x, pfrA[j].y), bfpack(pfrA[j].z, pfrA[j].w));
    float4 pfrB[4];
    {
      const int tb = (ii < 4) ? t0 + 3 : 9;   // tail: harmless re-read
#pragma unroll
      for (int j = 0; j < 4; ++j)
        pfrB[j] = *reinterpret_cast<const float4*>(xrow + tb * 256 + (sc + j * 16) * 4);
    }

    // ================= GEMM(t0+1) from xt[par][1] + LIF(t0+1) =================
    {
      f32x4 acc[2][4];
#pragma unroll
      for (int rt = 0; rt < 2; ++rt)
#pragma unroll
        for (int c = 0; c < 4; ++c) {
          f32x4 cc = { b1l[c], b1l[c], b1l[c], b1l[c] };
          acc[rt][c] = cc;
        }
      __builtin_amdgcn_s_setprio(1);
#pragma unroll
      for (int kk = 0; kk < 8; ++kk) {
        short8 a[2], bfr[4];
#pragma unroll
        for (int rt = 0; rt < 2; ++rt)
          a[rt] = *reinterpret_cast<const short8*>(
              &xt[par][1][kk >> 2][rt * 16 + l15][(kk & 3) * 32 + lq * 8]);
#pragma unroll
        for (int c = 0; c < 4; ++c) {
          if constexpr (USE_WS)
            bfr[c] = *reinterpret_cast<const short8*>(wb + c * 4096 + kk * 32);
          else
            bfr[c] = cvt_frag(wf + c * 4096 + kk * 32);
        }
#pragma unroll
        for (int rt = 0; rt < 2; ++rt)
#pragma unroll
          for (int c = 0; c < 4; ++c)
            acc[rt][c] = __builtin_amdgcn_mfma_f32_16x16x32_bf16(a[rt], bfr[c], acc[rt][c], 0, 0, 0);
      }
      __builtin_amdgcn_s_setprio(0);

#pragma unroll
      for (int rt = 0; rt < 2; ++rt) {
        float pr[4] = {0.f, 0.f, 0.f, 0.f};
#pragma unroll
        for (int c = 0; c < 4; ++c) {
          const int p = rt * 4 + c;
          if (p < 4) {
            f32x4* slot = reinterpret_cast<f32x4*>(&mem_lds[p][tid][0]);
            f32x4 mv = *slot;
            lif4(mv, acc[rt][c], w2l[c], pr);
            *slot = mv;
          } else if (p == 4) lif4(m4, acc[rt][c], w2l[c], pr);
          else if (p == 5)   lif4(m5, acc[rt][c], w2l[c], pr);
          else if (p == 6)   lif4(m6, acc[rt][c], w2l[c], pr);
          else               lif4(m7, acc[rt][c], w2l[c], pr);
        }
#pragma unroll
        for (int e = 0; e < 4; ++e) {
          float v = pr[e];
          v += __shfl_xor(v, 1); v += __shfl_xor(v, 2);
          v += __shfl_xor(v, 4); v += __shfl_xor(v, 8);
          if (l15 == 0) cur2_lds[t0 + 1][rt * 16 + lq * 4 + e][wave] = v;
        }
      }
    }

    // ---- pack+write t0+3 -> xt[npar][1] ----
#pragma unroll
    for (int j = 0; j < 4; ++j)
      *reinterpret_cast<uint2*>(&xt[npar][1][j >> 1][sr][(sc + (j & 1) * 16) * 4]) =
          make_uint2(bfpack(pfrB[j].x, pfrB[j].y), bfpack(pfrB[j].z, pfrB[j].w));

    __syncthreads();   // the ONLY barrier per 2t: xt[npar] visible; xt[par] reads done
  }

  // ---- deferred LIF2: 10-step chain, once, on 32 threads (final barrier = loop's last) ----
  if (tid < 32) {
    const float bias2 = b2[0];
    float mem2 = 0.f, spksum = 0.f;
#pragma unroll
    for (int t = 0; t < 10; ++t) {
      float c2 = bias2;
#pragma unroll
      for (int w = 0; w < 8; ++w) c2 += cur2_lds[t][tid][w];
      float m   = fmaf(mem2, 0.9f, c2);
      float spk = spike10(m);
      mem2   = m - spk;
      spksum += spk;
    }
    // final output sigmoid(spksum/10)
    float e = __builtin_amdgcn_exp2f(spksum * -0.14426950408f);
    out[b0 + tid] = __builtin_amdgcn_rcpf(1.0f + e);   // FLOAT32 output
  }
}

extern "C" void kernel_launch(void* const* d_in, const int* in_sizes, int n_in,
                              void* d_out, int out_size, void* d_ws, size_t ws_size,
                              hipStream_t stream) {
  const float* x  = (const float*)d_in[0];
  const float* W1 = (const float*)d_in[1];
  const float* b1 = (const float*)d_in[2];
  const float* W2 = (const float*)d_in[3];
  const float* b2 = (const float*)d_in[4];
  float* out = (float*)d_out;
  (void)in_sizes; (void)n_in;

  const int grid = out_size / 32;   // out_size == B == 32768 -> 1024 blocks

  if (ws_size >= 512 * 256 * sizeof(unsigned short)) {
    unsigned short* w1bf = (unsigned short*)d_ws;   // 256 KB
    w1_to_bf16<<<128, 256, 0, stream>>>(W1, w1bf);
    snn_main<true><<<grid, 512, 0, stream>>>(x, w1bf, W1, b1, W2, b2, out);
  } else {
    snn_main<false><<<grid, 512, 0, stream>>>(x, nullptr, W1, b1, W2, b2, out);
  }
}

// Round 31
// 166.357 us; speedup vs baseline: 1.2342x; 1.2342x over previous
//
#include <hip/hip_runtime.h>
#include <hip/hip_bf16.h>

// FraudSNN fused kernel: GEMM (bf16 MFMA) + LIF recurrence, T=10, F=256, H=512.
// R31 = R29 (165.8us best: post-barrier prefetch, 1 barrier/t, deferred LIF2,
// parity-dbuf xt, 78KB LDS, mem1 4 LDS + 4 reg planes, setprio, exp2 sigmoid)
// + LIF read-hoist: all 4 mem1-plane ds_read_b128 issued up front (independent,
// latencies overlap) before compute, writes batched after. R30's 2t structure
// (4th spill regression of that family) reverted.

typedef short short8 __attribute__((ext_vector_type(8)));
typedef float f32x4 __attribute__((ext_vector_type(4)));

__device__ __forceinline__ unsigned short bfbits(float f) {
  union { __hip_bfloat16 h; unsigned short u; } c;
  c.h = __float2bfloat16(f);   // hardware RNE
  return c.u;
}

__device__ __forceinline__ unsigned int bfpack(float a, float b) {
  return (unsigned int)bfbits(a) | ((unsigned int)bfbits(b) << 16);
}

// sigmoid(10*(m-1)) = 1 / (1 + exp2(14.4269504*(1-m)))
__device__ __forceinline__ float spike10(float m) {
  float e = __builtin_amdgcn_exp2f(fmaf(m, -14.4269504f, 14.4269504f));
  return __builtin_amdgcn_rcpf(1.0f + e);
}

__device__ __forceinline__ void lif4(f32x4& mv, const f32x4 av, float w2c, float pr[4]) {
#pragma unroll
  for (int e = 0; e < 4; ++e) {
    float m   = fmaf(mv[e], 0.9f, av[e]);     // beta*mem + cur1
    float spk = spike10(m);
    mv[e] = m - spk;
    pr[e] = fmaf(spk, w2c, pr[e]);
  }
}

__global__ void w1_to_bf16(const float* __restrict__ w1, unsigned short* __restrict__ o) {
  int i = blockIdx.x * 256 + threadIdx.x;      // 32768 float4s
  float4 v = reinterpret_cast<const float4*>(w1)[i];
  reinterpret_cast<uint2*>(o)[i] = make_uint2(bfpack(v.x, v.y), bfpack(v.z, v.w));
}

__device__ __forceinline__ short8 cvt_frag(const float* p) {
  const float4 v0 = *reinterpret_cast<const float4*>(p);
  const float4 v1 = *reinterpret_cast<const float4*>(p + 4);
  union { unsigned int u[4]; short8 s; } cv;
  cv.u[0] = bfpack(v0.x, v0.y);
  cv.u[1] = bfpack(v0.z, v0.w);
  cv.u[2] = bfpack(v1.x, v1.y);
  cv.u[3] = bfpack(v1.z, v1.w);
  return cv.s;
}

// 512 threads = 8 waves. Block: 32 batch rows; wave w owns 32 rows x h in [w*64, w*64+64).
template <bool USE_WS>
__global__
__attribute__((amdgpu_flat_work_group_size(512, 512)))
void snn_main(const float* __restrict__ x,
              const unsigned short* __restrict__ w1bf,  // bf16 W1 (if USE_WS)
              const float* __restrict__ w1f,            // fp32 W1 (fallback)
              const float* __restrict__ b1,
              const float* __restrict__ w2,
              const float* __restrict__ b2,
              float* __restrict__ out)
{
  __shared__ __align__(16) float mem_lds[4][512][4];          // 32,768 B, 0-conflict slots
  __shared__ __align__(16) unsigned short xt[2][2][32][132];  // [par][half][row][col] 33,792 B
  __shared__ float cur2_lds[10][32][9];                       // [t][row][wave] 11,520 B
                                                              // total 78,080 B

  const int tid  = threadIdx.x;
  const int lane = tid & 63;
  const int wave = tid >> 6;          // 0..7
  const int l15  = lane & 15;
  const int lq   = lane >> 4;         // 0..3
  const long b0  = (long)blockIdx.x * 32;
  const int h0   = wave * 64;         // 4 col-tiles of 16

  float w2l[4], b1l[4];
#pragma unroll
  for (int ct = 0; ct < 4; ++ct) {
    int h = h0 + ct * 16 + l15;
    w2l[ct] = w2[h];
    b1l[ct] = b1[h];
  }

#pragma unroll
  for (int p = 0; p < 4; ++p) {
    f32x4 z = {0.f, 0.f, 0.f, 0.f};
    *reinterpret_cast<f32x4*>(&mem_lds[p][tid][0]) = z;
  }
  // planes 4..7 (rt1, all ct) in registers: 16 VGPR
  f32x4 m4 = {0.f, 0.f, 0.f, 0.f}, m5 = m4, m6 = m4, m7 = m4;

  // staging: thread -> row sr (0..31), float4 col sc (0..15); 4 float4 per t
  const int sr = tid >> 4;
  const int sc = tid & 15;
  const float* xrow = x + (b0 + sr) * 2560;

  const unsigned short* wb = w1bf + (h0 + l15) * 256 + lq * 8;
  const float*          wf = w1f  + (h0 + l15) * 256 + lq * 8;

  // prologue: RAW load of t=0 (pfr = 4 float4 = 16 VGPR; packed lazily at use)
  float4 pfr[4];
#pragma unroll
  for (int j = 0; j < 4; ++j)
    pfr[j] = *reinterpret_cast<const float4*>(xrow + (sc + j * 16) * 4);

#pragma unroll 1
  for (int t = 0; t < 10; ++t) {
    const int par = t & 1;
    // ---- A: pack pfr(t) -> xt[par] (per-use waitcnt lands here, full-phase cover) ----
#pragma unroll
    for (int j = 0; j < 4; ++j)
      *reinterpret_cast<uint2*>(&xt[par][j >> 1][sr][(sc + (j & 1) * 16) * 4]) =
          make_uint2(bfpack(pfr[j].x, pfr[j].y), bfpack(pfr[j].z, pfr[j].w));
    // hoist kk=0 W1 fragments (consumed right after the barrier -> drain is correct)
    short8 bfr0[4];
#pragma unroll
    for (int c = 0; c < 4; ++c) {
      if constexpr (USE_WS) bfr0[c] = *reinterpret_cast<const short8*>(wb + c * 4096);
      else                  bfr0[c] = cvt_frag(wf + c * 4096);
    }
    __syncthreads();   // the ONLY per-t barrier: xt[par] visible

    // ---- issue pfr loads for t+1 AFTER the barrier (in flight under GEMM+LIF) ----
    {
      const int tn = (t < 9) ? t + 1 : 9;   // tail: harmless re-read
#pragma unroll
      for (int j = 0; j < 4; ++j)
        pfr[j] = *reinterpret_cast<const float4*>(xrow + tn * 256 + (sc + j * 16) * 4);
    }

    // ---- single-pass GEMM: acc[2][4] = 32 regs, 8 MFMA per kk ----
    f32x4 acc[2][4];
#pragma unroll
    for (int rt = 0; rt < 2; ++rt)
#pragma unroll
      for (int c = 0; c < 4; ++c) {
        f32x4 cc = { b1l[c], b1l[c], b1l[c], b1l[c] };
        acc[rt][c] = cc;
      }

    __builtin_amdgcn_s_setprio(1);
#pragma unroll
    for (int kk = 0; kk < 8; ++kk) {
      short8 a[2], bfr[4];
#pragma unroll
      for (int rt = 0; rt < 2; ++rt)
        a[rt] = *reinterpret_cast<const short8*>(
            &xt[par][kk >> 2][rt * 16 + l15][(kk & 3) * 32 + lq * 8]);
      if (kk == 0) {
#pragma unroll
        for (int c = 0; c < 4; ++c) bfr[c] = bfr0[c];
      } else {
#pragma unroll
        for (int c = 0; c < 4; ++c) {
          if constexpr (USE_WS)
            bfr[c] = *reinterpret_cast<const short8*>(wb + c * 4096 + kk * 32);
          else
            bfr[c] = cvt_frag(wf + c * 4096 + kk * 32);
        }
      }
#pragma unroll
      for (int rt = 0; rt < 2; ++rt)
#pragma unroll
        for (int c = 0; c < 4; ++c)
          acc[rt][c] = __builtin_amdgcn_mfma_f32_16x16x32_bf16(a[rt], bfr[c], acc[rt][c], 0, 0, 0);
    }
    __builtin_amdgcn_s_setprio(0);

    // ---- LIF1: issue ALL 4 LDS plane reads first (latencies overlap), then compute ----
    {
      f32x4 mv0 = *reinterpret_cast<f32x4*>(&mem_lds[0][tid][0]);
      f32x4 mv1 = *reinterpret_cast<f32x4*>(&mem_lds[1][tid][0]);
      f32x4 mv2 = *reinterpret_cast<f32x4*>(&mem_lds[2][tid][0]);
      f32x4 mv3 = *reinterpret_cast<f32x4*>(&mem_lds[3][tid][0]);

      float pr0[4] = {0.f, 0.f, 0.f, 0.f};
      lif4(mv0, acc[0][0], w2l[0], pr0);
      lif4(mv1, acc[0][1], w2l[1], pr0);
      lif4(mv2, acc[0][2], w2l[2], pr0);
      lif4(mv3, acc[0][3], w2l[3], pr0);

      float pr1[4] = {0.f, 0.f, 0.f, 0.f};
      lif4(m4, acc[1][0], w2l[0], pr1);
      lif4(m5, acc[1][1], w2l[1], pr1);
      lif4(m6, acc[1][2], w2l[2], pr1);
      lif4(m7, acc[1][3], w2l[3], pr1);

      *reinterpret_cast<f32x4*>(&mem_lds[0][tid][0]) = mv0;
      *reinterpret_cast<f32x4*>(&mem_lds[1][tid][0]) = mv1;
      *reinterpret_cast<f32x4*>(&mem_lds[2][tid][0]) = mv2;
      *reinterpret_cast<f32x4*>(&mem_lds[3][tid][0]) = mv3;

#pragma unroll
      for (int e = 0; e < 4; ++e) {
        float v = pr0[e];
        v += __shfl_xor(v, 1); v += __shfl_xor(v, 2);
        v += __shfl_xor(v, 4); v += __shfl_xor(v, 8);
        if (l15 == 0) cur2_lds[t][lq * 4 + e][wave] = v;
        float u = pr1[e];
        u += __shfl_xor(u, 1); u += __shfl_xor(u, 2);
        u += __shfl_xor(u, 4); u += __shfl_xor(u, 8);
        if (l15 == 0) cur2_lds[t][16 + lq * 4 + e][wave] = u;
      }
    }
    // no second barrier: cur2_lds[t] is not read until after the final barrier
  }

  __syncthreads();   // final: all cur2 partials visible

  // ---- deferred LIF2: 10-step chain, once, on 32 threads ----
  if (tid < 32) {
    const float bias2 = b2[0];
    float mem2 = 0.f, spksum = 0.f;
#pragma unroll
    for (int t = 0; t < 10; ++t) {
      float c2 = bias2;
#pragma unroll
      for (int w = 0; w < 8; ++w) c2 += cur2_lds[t][tid][w];
      float m   = fmaf(mem2, 0.9f, c2);
      float spk = spike10(m);
      mem2   = m - spk;
      spksum += spk;
    }
    // final output sigmoid(spksum/10)
    float e = __builtin_amdgcn_exp2f(spksum * -0.14426950408f);
    out[b0 + tid] = __builtin_amdgcn_rcpf(1.0f + e);   // FLOAT32 output
  }
}

extern "C" void kernel_launch(void* const* d_in, const int* in_sizes, int n_in,
                              void* d_out, int out_size, void* d_ws, size_t ws_size,
                              hipStream_t stream) {
  const float* x  = (const float*)d_in[0];
  const float* W1 = (const float*)d_in[1];
  const float* b1 = (const float*)d_in[2];
  const float* W2 = (const float*)d_in[3];
  const float* b2 = (const float*)d_in[4];
  float* out = (float*)d_out;
  (void)in_sizes; (void)n_in;

  const int grid = out_size / 32;   // out_size == B == 32768 -> 1024 blocks

  if (ws_size >= 512 * 256 * sizeof(unsigned short)) {
    unsigned short* w1bf = (unsigned short*)d_ws;   // 256 KB
    w1_to_bf16<<<128, 256, 0, stream>>>(W1, w1bf);
    snn_main<true><<<grid, 512, 0, stream>>>(x, w1bf, W1, b1, W2, b2, out);
  } else {
    snn_main<false><<<grid, 512, 0, stream>>>(x, nullptr, W1, b1, W2, b2, out);
  }
}